// Round 2
// baseline (498.548 us; speedup 1.0000x reference)
//
#include <hip/hip_runtime.h>

#define NL 8
#define BPL 524288
#define NB (NL * BPL)            // 4194304 buckets
#define NS 8
#define GRAV 9.8f
#define BUCKETS_PER_BLOCK 256
#define LAST_BLOCK0 ((NB - BPL) / BUCKETS_PER_BLOCK)   // 14336

// q for one spigot. 0.5*(tanh(h)+1) == 1/(1+exp(-2h)) -> v_exp + v_rcp.
__device__ __forceinline__ float spigot_q(float Hb, float sh, float sa, float th) {
    const float h   = fmaxf(0.0f, Hb - sh);
    const float e   = __expf(-2.0f * h);
    const float mod = __builtin_amdgcn_rcpf(1.0f + e);       // sigmoid(2h)
    return th * __builtin_amdgcn_sqrtf(2.0f * GRAV * h) * mod * sa;
}

// ---------------------------------------------------------------------------
// Fully fused: one thread per bucket (8 spigots). All global accesses are
// float4. outflow[b-1] is a pure function of inputs, so the block boundary
// is handled by recomputing the previous block's last bucket (8 scalar loads
// by lanes 0..7) -- no workspace, no second pass over H/outflows.
// ---------------------------------------------------------------------------
__global__ __launch_bounds__(256) void fused_kernel(
    const float* __restrict__ H,
    const float* __restrict__ S,
    const float* __restrict__ theta,
    const float* __restrict__ precip,
    float* __restrict__ H_new,
    float* __restrict__ s_q,
    float* __restrict__ net_out)
{
    const int b    = blockIdx.x * BUCKETS_PER_BLOCK + threadIdx.x;  // bucket
    const int lane = threadIdx.x & 63;
    const int wv   = threadIdx.x >> 6;

    __shared__ float s_last[4];   // each wave's last bucket outflow
    __shared__ float s_bp;        // previous block's last bucket outflow (or precip)
    __shared__ float s_part[4];   // net_out partials

    // ---- load this bucket's 8 spigots (vectorized) ----
    const float4* th4 = reinterpret_cast<const float4*>(theta);
    const float4* sv4 = reinterpret_cast<const float4*>(S);
    const float4 t0 = th4[b * 2 + 0];
    const float4 t1 = th4[b * 2 + 1];
    const float4 sA = sv4[b * 4 + 0];   // (h0,a0,h1,a1)
    const float4 sB = sv4[b * 4 + 1];   // (h2,a2,h3,a3)
    const float4 sC = sv4[b * 4 + 2];
    const float4 sD = sv4[b * 4 + 3];
    const float  Hb = H[b];

    float4 qA, qB;
    qA.x = spigot_q(Hb, sA.x, sA.y, t0.x);
    qA.y = spigot_q(Hb, sA.z, sA.w, t0.y);
    qA.z = spigot_q(Hb, sB.x, sB.y, t0.z);
    qA.w = spigot_q(Hb, sB.z, sB.w, t0.w);
    qB.x = spigot_q(Hb, sC.x, sC.y, t1.x);
    qB.y = spigot_q(Hb, sC.z, sC.w, t1.y);
    qB.z = spigot_q(Hb, sD.x, sD.y, t1.z);
    qB.w = spigot_q(Hb, sD.z, sD.w, t1.w);

    reinterpret_cast<float4*>(s_q)[b * 2 + 0] = qA;
    reinterpret_cast<float4*>(s_q)[b * 2 + 1] = qB;

    const float of = ((qA.x + qA.y) + (qA.z + qA.w)) +
                     ((qB.x + qB.y) + (qB.z + qB.w));

    // ---- cross-wave / cross-block previous-bucket outflow ----
    if (lane == 63) s_last[wv] = of;

    if (threadIdx.x < 8) {
        if (blockIdx.x == 0) {
            if (threadIdx.x == 0) s_bp = precip[0];
        } else {
            const int pb = blockIdx.x * BUCKETS_PER_BLOCK - 1;  // prev block's last bucket
            const int sp = pb * NS + threadIdx.x;
            const float2 sv = reinterpret_cast<const float2*>(S)[sp];
            float q = spigot_q(H[pb], sv.x, sv.y, theta[sp]);
            q += __shfl_xor(q, 1);
            q += __shfl_xor(q, 2);
            q += __shfl_xor(q, 4);
            if (threadIdx.x == 0) s_bp = q;
        }
    }
    __syncthreads();

    const float up = __shfl_up(of, 1);
    float prev;
    if (lane == 0) {
        prev = (wv == 0) ? s_bp : s_last[wv - 1];
    } else {
        prev = up;
    }

    H_new[b] = Hb + prev - of;

    // ---- network_outflow: last-layer blocks only (block-uniform branch) ----
    if (blockIdx.x >= LAST_BLOCK0) {
        float p = of;
        p += __shfl_xor(p, 1);
        p += __shfl_xor(p, 2);
        p += __shfl_xor(p, 4);
        p += __shfl_xor(p, 8);
        p += __shfl_xor(p, 16);
        p += __shfl_xor(p, 32);
        if (lane == 0) s_part[wv] = p;
        __syncthreads();
        if (threadIdx.x == 0) {
            atomicAdd(net_out, (s_part[0] + s_part[1]) + (s_part[2] + s_part[3]));
        }
    }
}

extern "C" void kernel_launch(void* const* d_in, const int* in_sizes, int n_in,
                              void* d_out, int out_size, void* d_ws, size_t ws_size,
                              hipStream_t stream) {
    const float* H      = (const float*)d_in[0];   // [NB]
    const float* S      = (const float*)d_in[1];   // [NB, NS, 2]
    const float* theta  = (const float*)d_in[2];   // [NB*NS]
    const float* precip = (const float*)d_in[3];   // scalar

    float* out     = (float*)d_out;
    float* H_new   = out;                               // [NB]
    float* s_q     = out + NB;                          // [NB, NS]
    float* net_out = out + NB + (size_t)NB * NS;        // scalar

    // scalar slot is poisoned 0xAA each run -> zero before atomics
    hipMemsetAsync(net_out, 0, sizeof(float), stream);

    fused_kernel<<<NB / BUCKETS_PER_BLOCK, 256, 0, stream>>>(
        H, S, theta, precip, H_new, s_q, net_out);
}